// Round 12
// baseline (123.349 us; speedup 1.0000x reference)
//
#include <hip/hip_runtime.h>
#include <math.h>

#define BATCH   256
#define NBLK    5000
#define NBLKP   5024      // padded row stride for g
#define IN_DIM  400000
#define D1      1024
#define D2      256
#define K1P     5120      // K for GEMM1, padded to multiple of 64
#define NSPLIT  16
#define ZK      (K1P / NSPLIT)   // 320 K-elems per split
#define ZSTEPS  (ZK / 64)        // 5 BK=64 steps per split
#define NBX     ((NBLK + 63) / 64)   // 79
#define SPGRID  1792              // 7 blocks/CU (21.5 KB LDS each)

typedef __attribute__((ext_vector_type(8))) short short8_t;
typedef __attribute__((ext_vector_type(4))) float f32x4;

static __device__ __forceinline__ unsigned short f2bf(float f) {
    union { float f; unsigned int u; } v; v.f = f;
    unsigned int u = v.u;
    return (unsigned short)((u + 0x7FFFu + ((u >> 16) & 1u)) >> 16);   // RNE
}

// ---------------------------------------------------------------------------
// Stage 1: sparse block dots — PERSISTENT grid-stride version (H2: amortize
// per-block setup over ~11 tiles/block like the 6.7 TB/s fill kernels).
// Per tile: stage 20KB x-span via contiguous nt loads -> LDS (84-stride,
// bank-spread), dot per 4-lane group against sv (L2-resident).
// ---------------------------------------------------------------------------
__global__ __launch_bounds__(256) void k_sparse(const float* __restrict__ x,
                                                const float* __restrict__ sv,
                                                float* __restrict__ g) {
    __shared__ float xs[64 * 84];          // 21504 B
    const int tid  = threadIdx.x;
    const int gidx = tid >> 2;
    const int s    = tid & 3;

    for (int t = blockIdx.x; t < NBX * BATCH; t += SPGRID) {
        const int bx = t % NBX;
        const int b  = t / NBX;
        const int j  = bx * 64 + gidx;
        const bool jv = (j < NBLK);

        // sv loads issued first (L2-resident): latency overlaps x staging
        float4 sva[5];
        if (jv) {
            const float4* sr = reinterpret_cast<const float4*>(sv + (size_t)j * 80);
#pragma unroll
            for (int r = 0; r < 5; ++r) sva[r] = sr[r * 4 + s];
        }

        // stage x span [bx*5120, +5120) floats, contiguous nt float4 loads
        const float* xrow = x + (size_t)b * IN_DIM + (size_t)bx * 5120;
        const int fmax = 100000 - bx * 1280;
#pragma unroll
        for (int i = 0; i < 5; ++i) {
            const int f = tid + i * 256;
            if (f < fmax) {
                const f32x4 v = __builtin_nontemporal_load(
                    reinterpret_cast<const f32x4*>(xrow + f * 4));
                const int jl = f / 20;
                const int m  = f % 20;
                *reinterpret_cast<f32x4*>(&xs[jl * 84 + m * 4]) = v;
            }
        }
        __syncthreads();

        if (jv) {
            const float4* xl = reinterpret_cast<const float4*>(&xs[gidx * 84]);
            float acc = 0.0f;
#pragma unroll
            for (int r = 0; r < 5; ++r) {
                const float4 xv = xl[r * 4 + s];
                const float4 sg = sva[r];
                acc += xv.x * sg.x + xv.y * sg.y + xv.z * sg.z + xv.w * sg.w;
            }
            acc += __shfl_xor(acc, 1);
            acc += __shfl_xor(acc, 2);
            if (s == 0) g[(size_t)b * NBLKP + j] = acc;
        }
        __syncthreads();   // xs consumed; safe to overwrite next iteration
    }
}

// ---------------------------------------------------------------------------
// Stage 2: LayerNorm (float4 loads); writes bf16 A [BATCH][K1P], zero pad.
// ---------------------------------------------------------------------------
__global__ __launch_bounds__(256) void k_ln(const float* __restrict__ g,
                                            const float* __restrict__ gamma,
                                            const float* __restrict__ beta,
                                            unsigned short* __restrict__ A) {
    const int b   = blockIdx.x;
    const int tid = threadIdx.x;
    const float* row = g + (size_t)b * NBLKP;
    float4 v[5];
    float s = 0.0f, ss = 0.0f;
#pragma unroll
    for (int i = 0; i < 5; ++i) {
        const int f4 = tid + i * 256;                 // over 1250 float4
        float4 vv = {0.f, 0.f, 0.f, 0.f};
        if (f4 < 1250) vv = *reinterpret_cast<const float4*>(row + f4 * 4);
        v[i] = vv;
        s  += vv.x + vv.y + vv.z + vv.w;
        ss += vv.x * vv.x + vv.y * vv.y + vv.z * vv.z + vv.w * vv.w;
    }
#pragma unroll
    for (int o = 32; o > 0; o >>= 1) {
        s  += __shfl_xor(s, o);
        ss += __shfl_xor(ss, o);
    }
    __shared__ float ls[4], lss[4];
    const int wid = tid >> 6;
    if ((tid & 63) == 0) { ls[wid] = s; lss[wid] = ss; }
    __syncthreads();
    s  = ls[0] + ls[1] + ls[2] + ls[3];
    ss = lss[0] + lss[1] + lss[2] + lss[3];
    const float mu  = s / (float)NBLK;
    const float var = ss / (float)NBLK - mu * mu;
    const float rs  = rsqrtf(var + 1e-5f);
    unsigned short* dst = A + (size_t)b * K1P;
#pragma unroll
    for (int i = 0; i < 5; ++i) {
        const int f4 = tid + i * 256;                 // over 1280 (covers pad)
        if (f4 < 1280) {
            const int c = f4 * 4;
            ushort4 o;
            if (f4 < 1250) {
                const float4 gm = *reinterpret_cast<const float4*>(gamma + c);
                const float4 bt = *reinterpret_cast<const float4*>(beta + c);
                o = { f2bf((v[i].x - mu) * rs * gm.x + bt.x),
                      f2bf((v[i].y - mu) * rs * gm.y + bt.y),
                      f2bf((v[i].z - mu) * rs * gm.z + bt.z),
                      f2bf((v[i].w - mu) * rs * gm.w + bt.w) };
            } else {
                o = ushort4{0, 0, 0, 0};
            }
            *reinterpret_cast<ushort4*>(dst + c) = o;
        }
    }
}

// ---------------------------------------------------------------------------
// GEMM1: M=256 x N=64 tile, split-K=16, 512 threads / 8 waves (2 waves/SIMD).
// W1 read once as fp32, bf16-converted in staging. acc[2][4] per wave.
// ---------------------------------------------------------------------------
__global__ __launch_bounds__(512) void k_gemm1(const unsigned short* __restrict__ A,
                                               const float* __restrict__ W1,
                                               float* __restrict__ C) {
    const int n0 = blockIdx.x * 64;
    const int z  = blockIdx.y;
    const int kbase = z * ZK;
    float* Cz = C + (size_t)z * BATCH * D1;

    __shared__ unsigned short As[256][72];
    __shared__ unsigned short Ws[64][72];

    const int tid  = threadIdx.x;
    const int wave = tid >> 6;
    const int lane = tid & 63;
    const int lr   = lane & 15;
    const int lk   = (lane >> 4) * 8;
    const int srow = tid >> 3;            // 0..63 (A rows srow + it*64)
    const int scol = (tid & 7) * 8;       // 0..56
    const int wrow = tid >> 3;            // 0..63 (W row)
    const int wcol = (tid & 7) * 8;       // 0..56

    const unsigned short* Ap = A + (size_t)srow * K1P + kbase + scol;
    const float* Wrow = W1 + (size_t)(n0 + wrow) * NBLK;

    short8_t pa[4];
    float4 pwf[2];
    auto loadA = [&](int t) {
#pragma unroll
        for (int it = 0; it < 4; ++it)
            pa[it] = *reinterpret_cast<const short8_t*>(Ap + (size_t)it * 64 * K1P + t * 64);
    };
    auto loadW = [&](int t) {
        const int k0 = kbase + t * 64 + wcol;
#pragma unroll
        for (int q = 0; q < 2; ++q) {
            const int k = k0 + q * 4;      // 4-aligned; NBLK%4==0
            pwf[q] = (k < NBLK) ? *reinterpret_cast<const float4*>(Wrow + k)
                                : float4{0.f, 0.f, 0.f, 0.f};
        }
    };

    loadA(0);
    loadW(0);

    f32x4 acc[2][4] = {};

    for (int t = 0; t < ZSTEPS; ++t) {
        __syncthreads();
#pragma unroll
        for (int it = 0; it < 4; ++it)
            *reinterpret_cast<short8_t*>(&As[srow + it * 64][scol]) = pa[it];
        {
            short8_t w0 = { (short)f2bf(pwf[0].x), (short)f2bf(pwf[0].y), (short)f2bf(pwf[0].z), (short)f2bf(pwf[0].w),
                            (short)f2bf(pwf[1].x), (short)f2bf(pwf[1].y), (short)f2bf(pwf[1].z), (short)f2bf(pwf[1].w) };
            *reinterpret_cast<short8_t*>(&Ws[wrow][wcol]) = w0;
        }
        __syncthreads();
        if (t + 1 < ZSTEPS) { loadA(t + 1); loadW(t + 1); }
#pragma unroll
        for (int kk = 0; kk < 64; kk += 32) {
            short8_t a[2], bf[4];
#pragma unroll
            for (int i = 0; i < 2; ++i)
                a[i] = *reinterpret_cast<const short8_t*>(&As[wave * 32 + i * 16 + lr][kk + lk]);
#pragma unroll
            for (int jj = 0; jj < 4; ++jj)
                bf[jj] = *reinterpret_cast<const short8_t*>(&Ws[jj * 16 + lr][kk + lk]);
#pragma unroll
            for (int i = 0; i < 2; ++i)
#pragma unroll
                for (int jj = 0; jj < 4; ++jj)
                    acc[i][jj] = __builtin_amdgcn_mfma_f32_16x16x32_bf16(a[i], bf[jj], acc[i][jj], 0, 0, 0);
        }
    }

    const int rbase = (lane >> 4) * 4;
#pragma unroll
    for (int i = 0; i < 2; ++i)
#pragma unroll
        for (int jj = 0; jj < 4; ++jj) {
            const int col = n0 + jj * 16 + lr;
#pragma unroll
            for (int r = 0; r < 4; ++r) {
                const int row = wave * 32 + i * 16 + rbase + r;
                Cz[(size_t)row * D1 + col] = acc[i][jj][r];
            }
        }
}

// ---------------------------------------------------------------------------
// Sum split-K partials + b1 -> bf16 A2; also converts W2 -> bf16.
// ---------------------------------------------------------------------------
__global__ __launch_bounds__(256) void k_fuse(const float* __restrict__ p,
                                              const float* __restrict__ b1,
                                              unsigned short* __restrict__ A2,
                                              const float* __restrict__ W2,
                                              unsigned short* __restrict__ W2b) {
    const int idx = (blockIdx.x * 256 + threadIdx.x) * 4;       // over 256*1024
    const int col = idx & (D1 - 1);
    const size_t S = (size_t)BATCH * D1;
    float4 bb = *reinterpret_cast<const float4*>(b1 + col);
    float sx = bb.x, sy = bb.y, sz = bb.z, sw = bb.w;
#pragma unroll
    for (int q = 0; q < NSPLIT; ++q) {
        float4 v = *reinterpret_cast<const float4*>(p + q * S + idx);
        sx += v.x; sy += v.y; sz += v.z; sw += v.w;
    }
    ushort4 o = { f2bf(sx), f2bf(sy), f2bf(sz), f2bf(sw) };
    *reinterpret_cast<ushort4*>(A2 + idx) = o;
    float4 wv = *reinterpret_cast<const float4*>(W2 + idx);
    ushort4 wo = { f2bf(wv.x), f2bf(wv.y), f2bf(wv.z), f2bf(wv.w) };
    *reinterpret_cast<ushort4*>(W2b + idx) = wo;
}

// ---------------------------------------------------------------------------
// Fused tail: out = sigmoid(A2 @ W2^T + b2) @ W3 + b3, h2 never materialized.
// 8 blocks x 512 threads (8 waves); wave w owns cols w*32..w*32+31.
// ---------------------------------------------------------------------------
__global__ __launch_bounds__(512) void k_tail(const unsigned short* __restrict__ A2,
                                              const unsigned short* __restrict__ W2b,
                                              const float* __restrict__ b2,
                                              const float* __restrict__ W3,
                                              const float* __restrict__ b3,
                                              float* __restrict__ out) {
    const int m0 = blockIdx.x * 32;
    __shared__ unsigned short As[32][72];
    __shared__ unsigned short Ws[256][72];
    __shared__ float red[8][32];

    const int tid  = threadIdx.x;
    const int wave = tid >> 6;
    const int lane = tid & 63;
    const int wc   = wave * 32;
    const int lr   = lane & 15;
    const int lk   = (lane >> 4) * 8;
    const int srow = tid >> 3;            // 0..63
    const int scol = (tid & 7) * 8;

    const unsigned short* Ap = A2 + (size_t)(m0 + srow) * D1 + scol;   // tid<256 only
    const unsigned short* Wp = W2b + (size_t)srow * D1 + scol;         // rows srow+64*it

    short8_t pa = {};
    short8_t pw[4];
    if (tid < 256) pa = *reinterpret_cast<const short8_t*>(Ap);
#pragma unroll
    for (int it = 0; it < 4; ++it)
        pw[it] = *reinterpret_cast<const short8_t*>(Wp + (size_t)it * 64 * D1);

    f32x4 acc[2][2] = {};

    for (int t = 0; t < 16; ++t) {
        __syncthreads();
        if (tid < 256) *reinterpret_cast<short8_t*>(&As[srow][scol]) = pa;
#pragma unroll
        for (int it = 0; it < 4; ++it)
            *reinterpret_cast<short8_t*>(&Ws[srow + it * 64][scol]) = pw[it];
        __syncthreads();
        if (t + 1 < 16) {
            const int ko = (t + 1) * 64;
            if (tid < 256) pa = *reinterpret_cast<const short8_t*>(Ap + ko);
#pragma unroll
            for (int it = 0; it < 4; ++it)
                pw[it] = *reinterpret_cast<const short8_t*>(Wp + (size_t)it * 64 * D1 + ko);
        }
#pragma unroll
        for (int kk = 0; kk < 64; kk += 32) {
            short8_t a0 = *reinterpret_cast<const short8_t*>(&As[lr][kk + lk]);
            short8_t a1 = *reinterpret_cast<const short8_t*>(&As[16 + lr][kk + lk]);
#pragma unroll
            for (int j = 0; j < 2; ++j) {
                short8_t bj = *reinterpret_cast<const short8_t*>(&Ws[wc + j * 16 + lr][kk + lk]);
                acc[0][j] = __builtin_amdgcn_mfma_f32_16x16x32_bf16(a0, bj, acc[0][j], 0, 0, 0);
                acc[1][j] = __builtin_amdgcn_mfma_f32_16x16x32_bf16(a1, bj, acc[1][j], 0, 0, 0);
            }
        }
    }

    float b2c[2], w3c[2];
#pragma unroll
    for (int j = 0; j < 2; ++j) {
        const int col = wc + j * 16 + lr;
        b2c[j] = b2[col];
        w3c[j] = W3[col];
    }
    const int rbase = (lane >> 4) * 4;
#pragma unroll
    for (int i = 0; i < 2; ++i) {
#pragma unroll
        for (int r = 0; r < 4; ++r) {
            float pv = 0.0f;
#pragma unroll
            for (int j = 0; j < 2; ++j) {
                const float h = acc[i][j][r] + b2c[j];
                pv += w3c[j] / (1.0f + __expf(-h));
            }
            pv += __shfl_xor(pv, 1);
            pv += __shfl_xor(pv, 2);
            pv += __shfl_xor(pv, 4);
            pv += __shfl_xor(pv, 8);
            if (lr == 0) red[wave][i * 16 + rbase + r] = pv;
        }
    }
    __syncthreads();
    if (tid < 32) {
        float s2 = 0.0f;
#pragma unroll
        for (int w = 0; w < 8; ++w) s2 += red[w][tid];
        out[m0 + tid] = s2 + b3[0];
    }
}

extern "C" void kernel_launch(void* const* d_in, const int* in_sizes, int n_in,
                              void* d_out, int out_size, void* d_ws, size_t ws_size,
                              hipStream_t stream) {
    const float* x     = (const float*)d_in[0];
    const float* sv    = (const float*)d_in[1];
    const float* gamma = (const float*)d_in[2];
    const float* beta  = (const float*)d_in[3];
    const float* W1    = (const float*)d_in[4];
    const float* b1    = (const float*)d_in[5];
    const float* W2    = (const float*)d_in[6];
    const float* b2    = (const float*)d_in[7];
    const float* W3    = (const float*)d_in[8];
    const float* b3    = (const float*)d_in[9];
    float* out = (float*)d_out;

    char* ws = (char*)d_ws;
    size_t off = 0;
    auto alloc = [&](size_t bytes) { char* p = ws + off; off = (off + bytes + 255) & ~(size_t)255; return p; };
    float*          g     = (float*)         alloc((size_t)BATCH * NBLKP * 4);       // 5.1 MB
    unsigned short* Ab    = (unsigned short*)alloc((size_t)BATCH * K1P * 2);         // 2.6 MB
    float*          out1p = (float*)         alloc((size_t)NSPLIT * BATCH * D1 * 4); // 16.8 MB
    unsigned short* A2b   = (unsigned short*)alloc((size_t)BATCH * D1 * 2);          // 0.5 MB
    unsigned short* W2b   = (unsigned short*)alloc((size_t)D2 * D1 * 2);             // 0.5 MB

    k_sparse<<<dim3(SPGRID), 256, 0, stream>>>(x, sv, g);
    k_ln<<<dim3(BATCH), 256, 0, stream>>>(g, gamma, beta, Ab);
    k_gemm1<<<dim3(D1 / 64, NSPLIT), 512, 0, stream>>>(Ab, W1, out1p);
    k_fuse<<<dim3(BATCH * D1 / (256 * 4)), 256, 0, stream>>>(out1p, b1, A2b, W2, W2b);
    k_tail<<<dim3(BATCH / 8), 512, 0, stream>>>(A2b, W2b, b2, W3, b3, out);
}

// Round 13
// 116.499 us; speedup vs baseline: 1.0588x; 1.0588x over previous
//
#include <hip/hip_runtime.h>
#include <math.h>

#define BATCH   256
#define NBLK    5000
#define NBLKP   5024      // padded row stride for g
#define IN_DIM  400000
#define D1      1024
#define D2      256
#define K1P     5120      // K for GEMM1, padded to multiple of 64
#define NSPLIT  16
#define ZK      (K1P / NSPLIT)   // 320 K-elems per split
#define ZSTEPS  (ZK / 64)        // 5 BK=64 steps per split
#define NBX     ((NBLK + 63) / 64)   // 79

typedef __attribute__((ext_vector_type(8))) short short8_t;
typedef __attribute__((ext_vector_type(4))) float f32x4;
typedef _Float16 half4v __attribute__((ext_vector_type(4)));

static __device__ __forceinline__ unsigned short f2bf(float f) {
    union { float f; unsigned int u; } v; v.f = f;
    unsigned int u = v.u;
    return (unsigned short)((u + 0x7FFFu + ((u >> 16) & 1u)) >> 16);   // RNE
}

// ---------------------------------------------------------------------------
// Stage 1: sparse block dots (R10 config — best measured: ~74 us, ~5.5 TB/s,
// the practical ceiling for this pattern). x staged through LDS with
// contiguous non-temporal wave loads; sv (L2-resident) issued pre-barrier.
// ---------------------------------------------------------------------------
__global__ __launch_bounds__(256) void k_sparse(const float* __restrict__ x,
                                                const float* __restrict__ sv,
                                                float* __restrict__ g) {
    __shared__ float xs[64 * 84];          // 21504 B
    const int bx  = blockIdx.x;
    const int b   = blockIdx.y;
    const int tid = threadIdx.x;
    const int gidx = tid >> 2;
    const int s    = tid & 3;
    const int j    = bx * 64 + gidx;
    const bool jv  = (j < NBLK);

    float4 sva[5];
    if (jv) {
        const float4* sr = reinterpret_cast<const float4*>(sv + (size_t)j * 80);
#pragma unroll
        for (int r = 0; r < 5; ++r) sva[r] = sr[r * 4 + s];
    }

    const float* xrow = x + (size_t)b * IN_DIM + (size_t)bx * 5120;
    const int fmax = 100000 - bx * 1280;   // valid float4 count in span
#pragma unroll
    for (int i = 0; i < 5; ++i) {
        const int f = tid + i * 256;
        if (f < fmax) {
            const f32x4 v = __builtin_nontemporal_load(
                reinterpret_cast<const f32x4*>(xrow + f * 4));
            const int jl = f / 20;
            const int m  = f % 20;
            *reinterpret_cast<f32x4*>(&xs[jl * 84 + m * 4]) = v;
        }
    }
    __syncthreads();

    if (!jv) return;
    const float4* xl = reinterpret_cast<const float4*>(&xs[gidx * 84]);
    float acc = 0.0f;
#pragma unroll
    for (int r = 0; r < 5; ++r) {
        const float4 xv = xl[r * 4 + s];
        const float4 sg = sva[r];
        acc += xv.x * sg.x + xv.y * sg.y + xv.z * sg.z + xv.w * sg.w;
    }
    acc += __shfl_xor(acc, 1);
    acc += __shfl_xor(acc, 2);
    if (s == 0) g[(size_t)b * NBLKP + j] = acc;
}

// ---------------------------------------------------------------------------
// Stage 2: LayerNorm (float4 loads); writes bf16 A [BATCH][K1P], zero pad.
// ---------------------------------------------------------------------------
__global__ __launch_bounds__(256) void k_ln(const float* __restrict__ g,
                                            const float* __restrict__ gamma,
                                            const float* __restrict__ beta,
                                            unsigned short* __restrict__ A) {
    const int b   = blockIdx.x;
    const int tid = threadIdx.x;
    const float* row = g + (size_t)b * NBLKP;
    float4 v[5];
    float s = 0.0f, ss = 0.0f;
#pragma unroll
    for (int i = 0; i < 5; ++i) {
        const int f4 = tid + i * 256;                 // over 1250 float4
        float4 vv = {0.f, 0.f, 0.f, 0.f};
        if (f4 < 1250) vv = *reinterpret_cast<const float4*>(row + f4 * 4);
        v[i] = vv;
        s  += vv.x + vv.y + vv.z + vv.w;
        ss += vv.x * vv.x + vv.y * vv.y + vv.z * vv.z + vv.w * vv.w;
    }
#pragma unroll
    for (int o = 32; o > 0; o >>= 1) {
        s  += __shfl_xor(s, o);
        ss += __shfl_xor(ss, o);
    }
    __shared__ float ls[4], lss[4];
    const int wid = tid >> 6;
    if ((tid & 63) == 0) { ls[wid] = s; lss[wid] = ss; }
    __syncthreads();
    s  = ls[0] + ls[1] + ls[2] + ls[3];
    ss = lss[0] + lss[1] + lss[2] + lss[3];
    const float mu  = s / (float)NBLK;
    const float var = ss / (float)NBLK - mu * mu;
    const float rs  = rsqrtf(var + 1e-5f);
    unsigned short* dst = A + (size_t)b * K1P;
#pragma unroll
    for (int i = 0; i < 5; ++i) {
        const int f4 = tid + i * 256;                 // over 1280 (covers pad)
        if (f4 < 1280) {
            const int c = f4 * 4;
            ushort4 o;
            if (f4 < 1250) {
                const float4 gm = *reinterpret_cast<const float4*>(gamma + c);
                const float4 bt = *reinterpret_cast<const float4*>(beta + c);
                o = { f2bf((v[i].x - mu) * rs * gm.x + bt.x),
                      f2bf((v[i].y - mu) * rs * gm.y + bt.y),
                      f2bf((v[i].z - mu) * rs * gm.z + bt.z),
                      f2bf((v[i].w - mu) * rs * gm.w + bt.w) };
            } else {
                o = ushort4{0, 0, 0, 0};
            }
            *reinterpret_cast<ushort4*>(dst + c) = o;
        }
    }
}

// ---------------------------------------------------------------------------
// GEMM1: M=256 x N=64 tile, split-K=16, 512 threads / 8 waves (2 waves/SIMD).
// W1 read once as fp32, bf16-converted in staging. acc[2][4] per wave.
// Partials written fp16 (error ~3e-4 after 16-way sum — negligible).
// ---------------------------------------------------------------------------
__global__ __launch_bounds__(512) void k_gemm1(const unsigned short* __restrict__ A,
                                               const float* __restrict__ W1,
                                               _Float16* __restrict__ C) {
    const int n0 = blockIdx.x * 64;
    const int z  = blockIdx.y;
    const int kbase = z * ZK;
    _Float16* Cz = C + (size_t)z * BATCH * D1;

    __shared__ unsigned short As[256][72];
    __shared__ unsigned short Ws[64][72];

    const int tid  = threadIdx.x;
    const int wave = tid >> 6;
    const int lane = tid & 63;
    const int lr   = lane & 15;
    const int lk   = (lane >> 4) * 8;
    const int srow = tid >> 3;            // 0..63 (A rows srow + it*64)
    const int scol = (tid & 7) * 8;       // 0..56
    const int wrow = tid >> 3;            // 0..63 (W row)
    const int wcol = (tid & 7) * 8;       // 0..56

    const unsigned short* Ap = A + (size_t)srow * K1P + kbase + scol;
    const float* Wrow = W1 + (size_t)(n0 + wrow) * NBLK;

    short8_t pa[4];
    float4 pwf[2];
    auto loadA = [&](int t) {
#pragma unroll
        for (int it = 0; it < 4; ++it)
            pa[it] = *reinterpret_cast<const short8_t*>(Ap + (size_t)it * 64 * K1P + t * 64);
    };
    auto loadW = [&](int t) {
        const int k0 = kbase + t * 64 + wcol;
#pragma unroll
        for (int q = 0; q < 2; ++q) {
            const int k = k0 + q * 4;      // 4-aligned; NBLK%4==0
            pwf[q] = (k < NBLK) ? *reinterpret_cast<const float4*>(Wrow + k)
                                : float4{0.f, 0.f, 0.f, 0.f};
        }
    };

    loadA(0);
    loadW(0);

    f32x4 acc[2][4] = {};

    for (int t = 0; t < ZSTEPS; ++t) {
        __syncthreads();
#pragma unroll
        for (int it = 0; it < 4; ++it)
            *reinterpret_cast<short8_t*>(&As[srow + it * 64][scol]) = pa[it];
        {
            short8_t w0 = { (short)f2bf(pwf[0].x), (short)f2bf(pwf[0].y), (short)f2bf(pwf[0].z), (short)f2bf(pwf[0].w),
                            (short)f2bf(pwf[1].x), (short)f2bf(pwf[1].y), (short)f2bf(pwf[1].z), (short)f2bf(pwf[1].w) };
            *reinterpret_cast<short8_t*>(&Ws[wrow][wcol]) = w0;
        }
        __syncthreads();
        if (t + 1 < ZSTEPS) { loadA(t + 1); loadW(t + 1); }
#pragma unroll
        for (int kk = 0; kk < 64; kk += 32) {
            short8_t a[2], bf[4];
#pragma unroll
            for (int i = 0; i < 2; ++i)
                a[i] = *reinterpret_cast<const short8_t*>(&As[wave * 32 + i * 16 + lr][kk + lk]);
#pragma unroll
            for (int jj = 0; jj < 4; ++jj)
                bf[jj] = *reinterpret_cast<const short8_t*>(&Ws[jj * 16 + lr][kk + lk]);
#pragma unroll
            for (int i = 0; i < 2; ++i)
#pragma unroll
                for (int jj = 0; jj < 4; ++jj)
                    acc[i][jj] = __builtin_amdgcn_mfma_f32_16x16x32_bf16(a[i], bf[jj], acc[i][jj], 0, 0, 0);
        }
    }

    const int rbase = (lane >> 4) * 4;
#pragma unroll
    for (int i = 0; i < 2; ++i)
#pragma unroll
        for (int jj = 0; jj < 4; ++jj) {
            const int col = n0 + jj * 16 + lr;
#pragma unroll
            for (int r = 0; r < 4; ++r) {
                const int row = wave * 32 + i * 16 + rbase + r;
                Cz[(size_t)row * D1 + col] = (_Float16)acc[i][jj][r];
            }
        }
}

// ---------------------------------------------------------------------------
// Sum fp16 split-K partials + b1 -> bf16 A2; also converts W2 -> bf16.
// ---------------------------------------------------------------------------
__global__ __launch_bounds__(256) void k_fuse(const _Float16* __restrict__ p,
                                              const float* __restrict__ b1,
                                              unsigned short* __restrict__ A2,
                                              const float* __restrict__ W2,
                                              unsigned short* __restrict__ W2b) {
    const int idx = (blockIdx.x * 256 + threadIdx.x) * 4;       // over 256*1024
    const int col = idx & (D1 - 1);
    const size_t S = (size_t)BATCH * D1;
    float4 bb = *reinterpret_cast<const float4*>(b1 + col);
    float sx = bb.x, sy = bb.y, sz = bb.z, sw = bb.w;
#pragma unroll
    for (int q = 0; q < NSPLIT; ++q) {
        half4v v = *reinterpret_cast<const half4v*>(p + q * S + idx);
        sx += (float)v.x; sy += (float)v.y; sz += (float)v.z; sw += (float)v.w;
    }
    ushort4 o = { f2bf(sx), f2bf(sy), f2bf(sz), f2bf(sw) };
    *reinterpret_cast<ushort4*>(A2 + idx) = o;
    float4 wv = *reinterpret_cast<const float4*>(W2 + idx);
    ushort4 wo = { f2bf(wv.x), f2bf(wv.y), f2bf(wv.z), f2bf(wv.w) };
    *reinterpret_cast<ushort4*>(W2b + idx) = wo;
}

// ---------------------------------------------------------------------------
// Fused tail: out = sigmoid(A2 @ W2^T + b2) @ W3 + b3, h2 never materialized.
// 8 blocks x 512 threads (8 waves); wave w owns cols w*32..w*32+31.
// ---------------------------------------------------------------------------
__global__ __launch_bounds__(512) void k_tail(const unsigned short* __restrict__ A2,
                                              const unsigned short* __restrict__ W2b,
                                              const float* __restrict__ b2,
                                              const float* __restrict__ W3,
                                              const float* __restrict__ b3,
                                              float* __restrict__ out) {
    const int m0 = blockIdx.x * 32;
    __shared__ unsigned short As[32][72];
    __shared__ unsigned short Ws[256][72];
    __shared__ float red[8][32];

    const int tid  = threadIdx.x;
    const int wave = tid >> 6;
    const int lane = tid & 63;
    const int wc   = wave * 32;
    const int lr   = lane & 15;
    const int lk   = (lane >> 4) * 8;
    const int srow = tid >> 3;            // 0..63
    const int scol = (tid & 7) * 8;

    const unsigned short* Ap = A2 + (size_t)(m0 + srow) * D1 + scol;   // tid<256 only
    const unsigned short* Wp = W2b + (size_t)srow * D1 + scol;         // rows srow+64*it

    short8_t pa = {};
    short8_t pw[4];
    if (tid < 256) pa = *reinterpret_cast<const short8_t*>(Ap);
#pragma unroll
    for (int it = 0; it < 4; ++it)
        pw[it] = *reinterpret_cast<const short8_t*>(Wp + (size_t)it * 64 * D1);

    f32x4 acc[2][2] = {};

    for (int t = 0; t < 16; ++t) {
        __syncthreads();
        if (tid < 256) *reinterpret_cast<short8_t*>(&As[srow][scol]) = pa;
#pragma unroll
        for (int it = 0; it < 4; ++it)
            *reinterpret_cast<short8_t*>(&Ws[srow + it * 64][scol]) = pw[it];
        __syncthreads();
        if (t + 1 < 16) {
            const int ko = (t + 1) * 64;
            if (tid < 256) pa = *reinterpret_cast<const short8_t*>(Ap + ko);
#pragma unroll
            for (int it = 0; it < 4; ++it)
                pw[it] = *reinterpret_cast<const short8_t*>(Wp + (size_t)it * 64 * D1 + ko);
        }
#pragma unroll
        for (int kk = 0; kk < 64; kk += 32) {
            short8_t a0 = *reinterpret_cast<const short8_t*>(&As[lr][kk + lk]);
            short8_t a1 = *reinterpret_cast<const short8_t*>(&As[16 + lr][kk + lk]);
#pragma unroll
            for (int j = 0; j < 2; ++j) {
                short8_t bj = *reinterpret_cast<const short8_t*>(&Ws[wc + j * 16 + lr][kk + lk]);
                acc[0][j] = __builtin_amdgcn_mfma_f32_16x16x32_bf16(a0, bj, acc[0][j], 0, 0, 0);
                acc[1][j] = __builtin_amdgcn_mfma_f32_16x16x32_bf16(a1, bj, acc[1][j], 0, 0, 0);
            }
        }
    }

    float b2c[2], w3c[2];
#pragma unroll
    for (int j = 0; j < 2; ++j) {
        const int col = wc + j * 16 + lr;
        b2c[j] = b2[col];
        w3c[j] = W3[col];
    }
    const int rbase = (lane >> 4) * 4;
#pragma unroll
    for (int i = 0; i < 2; ++i) {
#pragma unroll
        for (int r = 0; r < 4; ++r) {
            float pv = 0.0f;
#pragma unroll
            for (int j = 0; j < 2; ++j) {
                const float h = acc[i][j][r] + b2c[j];
                pv += w3c[j] / (1.0f + __expf(-h));
            }
            pv += __shfl_xor(pv, 1);
            pv += __shfl_xor(pv, 2);
            pv += __shfl_xor(pv, 4);
            pv += __shfl_xor(pv, 8);
            if (lr == 0) red[wave][i * 16 + rbase + r] = pv;
        }
    }
    __syncthreads();
    if (tid < 32) {
        float s2 = 0.0f;
#pragma unroll
        for (int w = 0; w < 8; ++w) s2 += red[w][tid];
        out[m0 + tid] = s2 + b3[0];
    }
}

extern "C" void kernel_launch(void* const* d_in, const int* in_sizes, int n_in,
                              void* d_out, int out_size, void* d_ws, size_t ws_size,
                              hipStream_t stream) {
    const float* x     = (const float*)d_in[0];
    const float* sv    = (const float*)d_in[1];
    const float* gamma = (const float*)d_in[2];
    const float* beta  = (const float*)d_in[3];
    const float* W1    = (const float*)d_in[4];
    const float* b1    = (const float*)d_in[5];
    const float* W2    = (const float*)d_in[6];
    const float* b2    = (const float*)d_in[7];
    const float* W3    = (const float*)d_in[8];
    const float* b3    = (const float*)d_in[9];
    float* out = (float*)d_out;

    char* ws = (char*)d_ws;
    size_t off = 0;
    auto alloc = [&](size_t bytes) { char* p = ws + off; off = (off + bytes + 255) & ~(size_t)255; return p; };
    float*          g     = (float*)         alloc((size_t)BATCH * NBLKP * 4);       // 5.1 MB
    unsigned short* Ab    = (unsigned short*)alloc((size_t)BATCH * K1P * 2);         // 2.6 MB
    _Float16*       out1p = (_Float16*)      alloc((size_t)NSPLIT * BATCH * D1 * 2); // 8.4 MB
    unsigned short* A2b   = (unsigned short*)alloc((size_t)BATCH * D1 * 2);          // 0.5 MB
    unsigned short* W2b   = (unsigned short*)alloc((size_t)D2 * D1 * 2);             // 0.5 MB

    k_sparse<<<dim3(NBX, BATCH), 256, 0, stream>>>(x, sv, g);
    k_ln<<<dim3(BATCH), 256, 0, stream>>>(g, gamma, beta, Ab);
    k_gemm1<<<dim3(D1 / 64, NSPLIT), 512, 0, stream>>>(Ab, W1, out1p);
    k_fuse<<<dim3(BATCH * D1 / (256 * 4)), 256, 0, stream>>>(out1p, b1, A2b, W2, W2b);
    k_tail<<<dim3(BATCH / 8), 512, 0, stream>>>(A2b, W2b, b2, W3, b3, out);
}